// Round 9
// baseline (52.939 us; speedup 1.0000x reference)
//
#include <hip/hip_runtime.h>
#include <math.h>

#define NT 4096
#define MODES 64
#define ROWS 2048       // B*Ci == B*Co
#define TWO_PI 6.283185307179586f
#define PI_F 3.14159265358979f

static __device__ __forceinline__ void rotm(float& wr, float& wi, float sr, float si) {
  float nr = fmaf(wr, sr, -wi * si);
  float ni = fmaf(wr, si,  wi * sr);
  wr = nr; wi = ni;
}

// ---------------------------------------------------------------------------
// K1 fused (round-6 structure):
//  blocks [0, 64*S): 8-fold CFT partials -> xfp[ts][rowblk(64)][k(64)][rl(32)]
//  blocks [64*S, 64*S+128): w transpose -> w_t[k][i*64+o]
// CFT: xf[row,k] = (1/4096) sum_t x[row,t] e^{-2pi i k t/4096}
//  Fold t = tl + 512 j: s_c(tl) = E_c + e^{-i pi c/4} O_c, c = k mod 8.
//  Thread: k in {k0+8q, q=0..7} (one class c8=k0), 1 row; 32 rows/block.
//  Twiddles: 8+8 REGISTER chains (A: even tl, B: odd tl) stepping by
//  e^{-2pi i 2k/4096}, seeded once per block from exact integer phases
//  (3 sincosf + constant-step q-chains). Replaces the LDS tw table ->
//  DS instructions per 2-tl drop 24 -> 8 (the round-6 DS bottleneck).
// ---------------------------------------------------------------------------
__global__ __launch_bounds__(256) void cft_fused_kernel(
    const float* __restrict__ x, float2* __restrict__ xfp,
    const float* __restrict__ w_real, const float* __restrict__ w_imag,
    float* __restrict__ wrt, float* __restrict__ wit, int S) {
  __shared__ __align__(16) char smem[16896];
  const int tid = threadIdx.x;
  const int nCft = 64 * S;

  if ((int)blockIdx.x >= nCft) {
    // ---- w transpose: treat w as A[4096][64]; 64x64 LDS-tiled transpose ----
    // (uses 64*65*4 = 16640 B <= 16896)
    float (*tile)[65] = (float (*)[65])smem;
    const int bx = (int)blockIdx.x - nCft;
    const int sel = bx >> 6;
    const int io0 = (bx & 63) * 64;
    const float* __restrict__ src = sel ? w_imag : w_real;
    float* __restrict__ dst = sel ? wit : wrt;
#pragma unroll
    for (int j = 0; j < 4; ++j) {
      const int idx = tid + j * 256;
      const int r = idx >> 4;
      const int kq = idx & 15;
      float4 v = ((const float4*)src)[(size_t)(io0 + r) * 16 + kq];
      tile[r][4 * kq + 0] = v.x; tile[r][4 * kq + 1] = v.y;
      tile[r][4 * kq + 2] = v.z; tile[r][4 * kq + 3] = v.w;
    }
    __syncthreads();
#pragma unroll
    for (int j = 0; j < 16; ++j) {
      const int idx = tid + j * 256;
      const int k = idx >> 6;
      const int r = idx & 63;
      dst[(size_t)k * 4096 + io0 + r] = tile[r][k];
    }
    return;
  }

  // ---- CFT ----
  float* xsf = (float*)smem;       // [32 rows][8 j][16 tl], row stride 132
  const int k0 = tid & 7;          // class c8 = k0; k = k0 + 8q
  const int rg = tid >> 3;         // row 0..31
  const int C = 512 / S;           // tl per split (32 when S=16)
  const int rowblk = (int)blockIdx.x / S;
  const int ts = (int)blockIdx.x % S;
  const int row0 = rowblk * 32;
  const int tl0b = ts * C;

  const int c4 = k0 & 3;
  const float p  = (c4 & 1) ? -1.f : 1.f;
  const float qc = (c4 == 0) ? 1.f : ((c4 == 2) ? -1.f : 0.f);
  const float rc = (c4 == 1) ? -1.f : ((c4 == 3) ? 1.f : 0.f);
  float Aw, Bw;   // e^{-i pi c8/4}
  sincosf(-PI_F * (float)k0 * 0.25f, &Bw, &Aw);

  // ---- twiddle chain seeds (exact integer phases; q-chains with constant
  //      steps e^{-2pi i 8/4096}, e^{-2pi i 16/4096}) ----
  float wAr[8], wAi[8], wBr[8], wBi[8], s2r[8], s2i[8];
  {
    float bAr, bAi, m8r, m8i, b1r, b1i, b2r, b2i;
    sincosf(-TWO_PI * (float)((k0 * tl0b) & (NT - 1)) / (float)NT, &bAi, &bAr);
    sincosf(-TWO_PI * (float)((8 * tl0b) & (NT - 1)) / (float)NT, &m8i, &m8r);
    sincosf(-TWO_PI * (float)k0 / (float)NT, &b1i, &b1r);
    sincosf(-TWO_PI * (float)(2 * k0) / (float)NT, &b2i, &b2r);
    const float c8r = 0.9999247018391445f,  c8i = -0.0122715382857199f;  // e^{-i2pi*8/4096}
    const float c16r = 0.9996988186962042f, c16i = -0.0245412285229123f; // e^{-i2pi*16/4096}
    float aR = bAr, aI = bAi;      // wA[q] = e^{-i th k_q tl0b}
    float s1R = b1r, s1I = b1i;    // step1[q] = e^{-i th k_q}
    float t2R = b2r, t2I = b2i;    // step2[q] = e^{-i th 2 k_q}
#pragma unroll
    for (int q = 0; q < 8; ++q) {
      wAr[q] = aR; wAi[q] = aI;
      wBr[q] = fmaf(aR, s1R, -aI * s1I);   // wB = wA * step1
      wBi[q] = fmaf(aR, s1I,  aI * s1R);
      s2r[q] = t2R; s2i[q] = t2I;
      rotm(aR, aI, m8r, m8i);
      rotm(s1R, s1I, c8r, c8i);
      rotm(t2R, t2I, c16r, c16i);
    }
  }

  float ar[8] = {0.f,0.f,0.f,0.f,0.f,0.f,0.f,0.f};
  float ai[8] = {0.f,0.f,0.f,0.f,0.f,0.f,0.f,0.f};

  const float4* __restrict__ xg4 = (const float4*)x;
  const float2* bp = (const float2*)(xsf + rg * 132);

  for (int sub = 0; sub < C / 16; ++sub) {
    const int tl0 = tl0b + sub * 16;
    __syncthreads();
    // stage 32 rows x 8 j x 16 tl = 1024 float4-quarters; 4 float4 per thread.
#pragma unroll
    for (int it = 0; it < 4; ++it) {
      const int idx = tid + it * 256;
      const int tlf = idx & 3;
      const int j = (idx >> 2) & 7;
      const int row = idx >> 5;
      ((float4*)xsf)[row * 33 + j * 4 + tlf] =
          xg4[(size_t)(row0 + row) * (NT / 4) + j * 128 + (tl0 >> 2) + tlf];
    }
    __syncthreads();
#pragma unroll 2
    for (int tt = 0; tt < 8; ++tt) {
      float2 v[8];
#pragma unroll
      for (int j = 0; j < 8; ++j) v[j] = bp[j * 8 + tt];
#pragma unroll
      for (int par = 0; par < 2; ++par) {
        const float x0 = par ? v[0].y : v[0].x;
        const float x1 = par ? v[1].y : v[1].x;
        const float x2 = par ? v[2].y : v[2].x;
        const float x3 = par ? v[3].y : v[3].x;
        const float x4 = par ? v[4].y : v[4].x;
        const float x5 = par ? v[5].y : v[5].x;
        const float x6 = par ? v[6].y : v[6].x;
        const float x7 = par ? v[7].y : v[7].x;
        const float ue = fmaf(p, x4, x0), ve = fmaf(p, x6, x2);
        const float Er = fmaf(qc, ve, ue), Ei = rc * ve;
        const float uo = fmaf(p, x5, x1), vo = fmaf(p, x7, x3);
        const float Or_ = fmaf(qc, vo, uo), Oi_ = rc * vo;
        float sr = fmaf(Aw, Or_, Er); sr = fmaf(-Bw, Oi_, sr);
        float si = fmaf(Aw, Oi_, Ei); si = fmaf( Bw, Or_, si);
#pragma unroll
        for (int q = 0; q < 8; ++q) {
          const float wr = par ? wBr[q] : wAr[q];
          const float wi = par ? wBi[q] : wAi[q];
          ar[q] = fmaf(sr, wr, ar[q]); ar[q] = fmaf(-si, wi, ar[q]);
          ai[q] = fmaf(sr, wi, ai[q]); ai[q] = fmaf( si, wr, ai[q]);
        }
      }
      // advance both chains by step2 (one even-tl and one odd-tl step)
#pragma unroll
      for (int q = 0; q < 8; ++q) {
        rotm(wAr[q], wAi[q], s2r[q], s2i[q]);
        rotm(wBr[q], wBi[q], s2r[q], s2i[q]);
      }
    }
  }
  const float dt = 1.0f / (float)NT;
  const size_t base = ((size_t)ts * 64 + rowblk) * 64;
#pragma unroll
  for (int q = 0; q < 8; ++q) {
    xfp[(base + k0 + 8 * q) * 32 + rg] = make_float2(ar[q] * dt, ai[q] * dt);
  }
}

// ---------------------------------------------------------------------------
// K2: sum the S partials (coalesced) + spectral mix from LDS (round-6 verbatim).
//   yf[b,o,k] = sum_i xf[b,i,k] * W[i,o,k]
// grid = 512: k = bx&63, bq = bx>>6 (4 b's = 256 rows each).
// ---------------------------------------------------------------------------
__global__ __launch_bounds__(256) void mix_kernel(
    const float* __restrict__ wrt, const float* __restrict__ wit,
    const float2* __restrict__ xfp, float2* __restrict__ yf_t, int S) {
  __shared__ float2 wsc[4096];
  __shared__ float2 xsh[256];
  const int k = blockIdx.x & 63;
  const int bq = blockIdx.x >> 6;
  const int tid = threadIdx.x;
#pragma unroll
  for (int j = 0; j < 4; ++j) {
    const int idx = tid + 256 * j;
    float4 vr = ((const float4*)(wrt + (size_t)k * 4096))[idx];
    float4 vi = ((const float4*)(wit + (size_t)k * 4096))[idx];
    wsc[4 * idx + 0] = make_float2(vr.x, vi.x);
    wsc[4 * idx + 1] = make_float2(vr.y, vi.y);
    wsc[4 * idx + 2] = make_float2(vr.z, vi.z);
    wsc[4 * idx + 3] = make_float2(vr.w, vi.w);
  }
  {
    const int R = bq * 256 + tid;        // global row = b*64 + i
    const int rowblk = R >> 5;
    const int rl = R & 31;
    float2 acc = make_float2(0.f, 0.f);
    for (int s = 0; s < S; ++s) {
      float2 v = xfp[(((size_t)s * 64 + rowblk) * 64 + k) * 32 + rl];
      acc.x += v.x; acc.y += v.y;
    }
    xsh[tid] = acc;
  }
  __syncthreads();
  const int o = tid & 63;
  const int bl = tid >> 6;
  float accr = 0.f, acci = 0.f;
#pragma unroll 8
  for (int i = 0; i < 64; ++i) {
    const float2 xv = xsh[bl * 64 + i];  // broadcast (bl uniform per wave)
    const float2 w = wsc[i * 64 + o];
    accr = fmaf(xv.x, w.x, accr); accr = fmaf(-xv.y, w.y, accr);
    acci = fmaf(xv.x, w.y, acci); acci = fmaf( xv.y, w.x, acci);
  }
  yf_t[(size_t)k * ROWS + bq * 256 + bl * 64 + o] = make_float2(accr, acci);
}

// ---------------------------------------------------------------------------
// K3: 8-fold ICFT with fftshift pairing. Math identical to round 6; the
// inner-loop LDS reads (256 ds_read_b64/wave -> the round-6 DS bottleneck)
// are replaced by a per-lane register copy + v_readlane broadcast:
// lane L holds yf[k=L] for the block's 4 rows; k is wave-uniform so
// readlane(., k) is a zero-DS SGPR broadcast.
// grid = 1024: 512 rowgroups (4 rows) x 2 tl-chunks (256 each).
// ---------------------------------------------------------------------------
static __device__ __forceinline__ float rlane(float v, int k) {
  return __int_as_float(__builtin_amdgcn_readlane(__float_as_int(v), k));
}

__global__ __launch_bounds__(256) void icft_kernel(const float2* __restrict__ yf_t,
                                                   float* __restrict__ out) {
  __shared__ float2 ysh[4][66];
  const int rgrp = blockIdx.x >> 1;
  const int tc = blockIdx.x & 1;
  const int row0 = rgrp * 4;
  const int tid = threadIdx.x;
  {
    const int k = tid >> 2;
    const int r = tid & 3;
    ysh[r][k] = yf_t[(size_t)k * ROWS + row0 + r];
  }
  __syncthreads();
  // per-lane copy: lane L holds y[k=L] for rows 0..3
  const int lane = tid & 63;
  float yLr[4], yLi[4];
#pragma unroll
  for (int r = 0; r < 4; ++r) {
    const float2 y = ysh[r][lane];
    yLr[r] = y.x; yLi[r] = y.y;
  }
  const int tl = tc * 256 + tid;
  float stepr, stepi;
  sincosf(TWO_PI * (float)tl / (float)NT, &stepi, &stepr);
  float wr = 1.f, wi = 0.f;
  float Gr[8][4] = {{0.f}};
  float Gi[8][4] = {{0.f}};   // [0],[4] unused -> dead after unroll
  for (int m = 0; m < 8; ++m) {
#pragma unroll
    for (int cc = 0; cc < 8; ++cc) {
      const int k = 8 * m + cc;
#pragma unroll
      for (int r = 0; r < 4; ++r) {
        const float yx = rlane(yLr[r], k);   // SGPR broadcast, no DS
        const float yy = rlane(yLi[r], k);
        Gr[cc][r] = fmaf(yx, wr, Gr[cc][r]);
        Gr[cc][r] = fmaf(-yy, wi, Gr[cc][r]);
        if (cc != 0 && cc != 4) {
          Gi[cc][r] = fmaf(yx, wi, Gi[cc][r]);
          Gi[cc][r] = fmaf(yy, wr, Gi[cc][r]);
        }
      }
      rotm(wr, wi, stepr, stepi);
    }
  }
  const float KK = 0.7071067811865476f;
  const float sgn = (tl & 1) ? -1.f : 1.f;
#pragma unroll
  for (int r = 0; r < 4; ++r) {
    const float Ae = (Gr[0][r] + Gr[2][r]) + (Gr[4][r] + Gr[6][r]);
    const float Ao = (Gr[1][r] + Gr[3][r]) + (Gr[5][r] + Gr[7][r]);
    const float A2 = (Gr[0][r] - Gr[2][r]) + (Gr[4][r] - Gr[6][r]);
    const float B2 = (Gi[1][r] - Gi[3][r]) + (Gi[5][r] - Gi[7][r]);
    const float P  = Gr[0][r] - Gr[4][r];
    const float Qr = (Gr[1][r] - Gr[3][r]) - (Gr[5][r] - Gr[7][r]);
    const float R  = Gi[6][r] - Gi[2][r];
    const float Qi = (Gi[5][r] - Gi[1][r]) + (Gi[7][r] - Gi[3][r]);
    const float U = P + R, V = P - R;
    const float W1 = KK * (Qr + Qi), W2 = KK * (Qr - Qi);
    float* op = out + (size_t)(row0 + r) * NT + tl;
    op[0]    = sgn * (Ae + Ao);
    op[512]  = sgn * (U + W1);
    op[1024] = sgn * (A2 - B2);
    op[1536] = sgn * (V - W2);
    op[2048] = sgn * (Ae - Ao);
    op[2560] = sgn * (U - W1);
    op[3072] = sgn * (A2 + B2);
    op[3584] = sgn * (V + W2);
  }
}

extern "C" void kernel_launch(void* const* d_in, const int* in_sizes, int n_in,
                              void* d_out, int out_size, void* d_ws, size_t ws_size,
                              hipStream_t stream) {
  const float* x      = (const float*)d_in[0];
  const float* w_real = (const float*)d_in[1];
  const float* w_imag = (const float*)d_in[2];
  float* out = (float*)d_out;

  const size_t MB = (size_t)ROWS * MODES * sizeof(float2);  // 1 MiB units
  int S = 16;
  while (S > 4 && (size_t)(S + 4) * MB > ws_size) S >>= 1;

  char* wsp = (char*)d_ws;
  float2* xfp  = (float2*)wsp;                        // S MB: [ts][rowblk][k][rl]
  float2* yf_t = (float2*)(wsp + (size_t)S * MB);     // 2 MB: [k][row]
  float*  wrt  = (float*)(wsp + (size_t)(S + 2) * MB);
  float*  wit  = (float*)(wsp + (size_t)(S + 3) * MB);

  cft_fused_kernel<<<64 * S + 128, 256, 0, stream>>>(x, xfp, w_real, w_imag,
                                                     wrt, wit, S);
  mix_kernel<<<512, 256, 0, stream>>>(wrt, wit, xfp, yf_t, S);
  icft_kernel<<<1024, 256, 0, stream>>>(yf_t, out);
}

// Round 12
// 45.999 us; speedup vs baseline: 1.1509x; 1.1509x over previous
//
#include <hip/hip_runtime.h>
#include <math.h>

#define NT 4096
#define MODES 64
#define ROWS 2048       // B*Ci == B*Co
#define TWO_PI 6.283185307179586f

typedef __attribute__((ext_vector_type(8))) short bf16x8;   // 8 bf16 (4 VGPRs)
typedef __attribute__((ext_vector_type(4))) float f32x4;    // MFMA acc

static __device__ __forceinline__ void rotm(float& wr, float& wi, float sr, float si) {
  float nr = fmaf(wr, sr, -wi * si);
  float ni = fmaf(wr, si,  wi * sr);
  wr = nr; wi = ni;
}

static __device__ __forceinline__ unsigned short bf16rn(float x) {
  unsigned u = __float_as_uint(x);
  u += 0x7FFFu + ((u >> 16) & 1u);   // round-to-nearest-even
  return (unsigned short)(u >> 16);
}

// ---------------------------------------------------------------------------
// K0: generate B table: Bg[n][t] (bf16, n-major), n<64: cos(2pi n t/4096)/4096,
//     n>=64: -sin(2pi (n-64) t/4096)/4096.  (CFT basis x dt, exact int phases.)
// 256 blocks x 256 threads x 8 t each.
// ---------------------------------------------------------------------------
__global__ __launch_bounds__(256) void bgen_kernel(unsigned short* __restrict__ Bg) {
  const int e0 = ((int)blockIdx.x * 256 + (int)threadIdx.x) * 8;
  const int n = e0 >> 12;
  const int t0 = e0 & 4095;
  const int k = (n < 64) ? n : (n - 64);
  bf16x8 pack;
#pragma unroll
  for (int j = 0; j < 8; ++j) {
    const int ph = (k * (t0 + j)) & (NT - 1);
    float s, c;
    sincosf(TWO_PI * (float)ph / (float)NT, &s, &c);
    const float v = ((n < 64) ? c : -s) * (1.0f / (float)NT);
    pack[j] = (short)bf16rn(v);
  }
  *(bf16x8*)(Bg + e0) = pack;
}

// ---------------------------------------------------------------------------
// K1: MFMA CFT partials + fused w-transpose.
//  blocks [0, 64*S): M-tile (32 rows) x K-chunk ts (4096/S t) ->
//     xfp[ts][rowblk][plane(re/im)][k][rl] (fp32)
//  blocks [64*S, +128): w transpose -> w_t[k][i*64+o] (round-6 verbatim)
//  GEMM: D[32,128] += (Xh + Xl)[32,64] x B[64,128] per 64-t sub-step,
//  v_mfma_f32_16x16x32_bf16, 4 waves x (2 m-tiles x 2 n-tiles).
//  LDS XOR swizzle (col16 ^= row&7) on A and B -> 2-way (free) frag reads.
//  ROUND-10 BUG FIX: B staging now covers ALL 8 k-units per n (was 4 ->
//  half the tile uninitialized -> NaN).
// ---------------------------------------------------------------------------
__global__ __launch_bounds__(256) void cft_mfma_kernel(
    const float* __restrict__ x, const unsigned short* __restrict__ Bg,
    float* __restrict__ xfp,
    const float* __restrict__ w_real, const float* __restrict__ w_imag,
    float* __restrict__ wrt, float* __restrict__ wit, int S) {
  __shared__ __align__(16) char smem[24576];
  const int tid = threadIdx.x;
  const int nCft = 64 * S;

  if ((int)blockIdx.x >= nCft) {
    // ---- w transpose (round-6 verbatim; 16640 B <= 24576) ----
    float (*tile)[65] = (float (*)[65])smem;
    const int bx = (int)blockIdx.x - nCft;
    const int sel = bx >> 6;
    const int io0 = (bx & 63) * 64;
    const float* __restrict__ src = sel ? w_imag : w_real;
    float* __restrict__ dst = sel ? wit : wrt;
#pragma unroll
    for (int j = 0; j < 4; ++j) {
      const int idx = tid + j * 256;
      const int r = idx >> 4;
      const int kq = idx & 15;
      float4 v = ((const float4*)src)[(size_t)(io0 + r) * 16 + kq];
      tile[r][4 * kq + 0] = v.x; tile[r][4 * kq + 1] = v.y;
      tile[r][4 * kq + 2] = v.z; tile[r][4 * kq + 3] = v.w;
    }
    __syncthreads();
#pragma unroll
    for (int j = 0; j < 16; ++j) {
      const int idx = tid + j * 256;
      const int k = idx >> 6;
      const int r = idx & 63;
      dst[(size_t)k * 4096 + io0 + r] = tile[r][k];
    }
    return;
  }

  // LDS: Ah [32 rows][64 k] bf16 (4 KB) | Al (4 KB) | Bs [128 n][64 k] (16 KB)
  unsigned short* Ah = (unsigned short*)smem;
  unsigned short* Al = (unsigned short*)(smem + 4096);
  unsigned short* Bs = (unsigned short*)(smem + 8192);

  const int rowblk = (int)blockIdx.x / S;
  const int ts = (int)blockIdx.x % S;
  const int row0 = rowblk * 32;
  const int t0 = ts * (NT / S);
  const int subs = (NT / S) / 64;

  const int lane = tid & 63;
  const int w = tid >> 6;

  f32x4 acc[2][2];
#pragma unroll
  for (int mt = 0; mt < 2; ++mt)
#pragma unroll
    for (int nt = 0; nt < 2; ++nt) acc[mt][nt] = (f32x4){0.f, 0.f, 0.f, 0.f};

  const int aru = tid & 7;        // A k-unit (8 t = 16 B)
  const int arow = tid >> 3;      // A row 0..31

  for (int sub = 0; sub < subs; ++sub) {
    const int tb = t0 + sub * 64;
    __syncthreads();
    {  // A stage: x[row0+arow][tb+aru*8 ..+8] fp32 -> bf16 hi/lo, swizzled
      const float* xp = x + (size_t)(row0 + arow) * NT + tb + aru * 8;
      const float4 v0 = *(const float4*)xp;
      const float4 v1 = *(const float4*)(xp + 4);
      float xv[8] = {v0.x, v0.y, v0.z, v0.w, v1.x, v1.y, v1.z, v1.w};
      bf16x8 ph, pl;
#pragma unroll
      for (int j = 0; j < 8; ++j) {
        const unsigned short h = bf16rn(xv[j]);
        ph[j] = (short)h;
        const float hf = __uint_as_float((unsigned)h << 16);
        pl[j] = (short)bf16rn(xv[j] - hf);
      }
      const int col = (aru ^ (arow & 7)) * 8;
      *(bf16x8*)(Ah + arow * 64 + col) = ph;
      *(bf16x8*)(Al + arow * 64 + col) = pl;
    }
    // B stage: ALL 128 n x 8 k-units (1024 chunks, 4 per thread), coalesced.
#pragma unroll
    for (int it = 0; it < 4; ++it) {
      const int idx = tid + it * 256;   // 0..1023
      const int ku = idx & 7;
      const int n = idx >> 3;           // 0..127
      const bf16x8 v = *(const bf16x8*)(Bg + (size_t)n * NT + tb + ku * 8);
      const int col = (ku ^ (n & 7)) * 8;
      *(bf16x8*)(Bs + n * 64 + col) = v;
    }
    __syncthreads();
    const int kg = lane >> 4;     // fragment k-group 0..3
#pragma unroll
    for (int ks = 0; ks < 2; ++ks) {
      bf16x8 bf[2];
#pragma unroll
      for (int nt = 0; nt < 2; ++nt) {
        const int n = w * 32 + nt * 16 + (lane & 15);
        const int col = ((ks * 4 + kg) ^ (n & 7)) * 8;
        bf[nt] = *(const bf16x8*)(Bs + n * 64 + col);
      }
#pragma unroll
      for (int mt = 0; mt < 2; ++mt) {
        const int row = mt * 16 + (lane & 15);
        const int col = ((ks * 4 + kg) ^ (row & 7)) * 8;
        const bf16x8 ah = *(const bf16x8*)(Ah + row * 64 + col);
        const bf16x8 al = *(const bf16x8*)(Al + row * 64 + col);
#pragma unroll
        for (int nt = 0; nt < 2; ++nt) {
          acc[mt][nt] = __builtin_amdgcn_mfma_f32_16x16x32_bf16(ah, bf[nt], acc[mt][nt], 0, 0, 0);
          acc[mt][nt] = __builtin_amdgcn_mfma_f32_16x16x32_bf16(al, bf[nt], acc[mt][nt], 0, 0, 0);
        }
      }
    }
  }
  // store partials: [ts][rowblk][plane][k][rl] floats; rl%4==0 -> float4
  const int nb = w * 32 + (lane & 15);
#pragma unroll
  for (int nt = 0; nt < 2; ++nt) {
    const int n = nb + nt * 16;
    const int plane = n >> 6;
    const int kk = n & 63;
#pragma unroll
    for (int mt = 0; mt < 2; ++mt) {
      const int rl = mt * 16 + (lane >> 4) * 4;
      float4 st = {acc[mt][nt][0], acc[mt][nt][1], acc[mt][nt][2], acc[mt][nt][3]};
      ((float4*)xfp)[((((size_t)ts * 64 + rowblk) * 2 + plane) * 64 + kk) * 8 + (rl >> 2)] = st;
    }
  }
}

// ---------------------------------------------------------------------------
// K2: sum the S partials (coalesced, two planes) + spectral mix from LDS.
//   yf[b,o,k] = sum_i xf[b,i,k] * W[i,o,k]
// grid = 512: k = bx&63, bq = bx>>6 (4 b's = 256 rows each).
// ---------------------------------------------------------------------------
__global__ __launch_bounds__(256) void mix_kernel(
    const float* __restrict__ wrt, const float* __restrict__ wit,
    const float* __restrict__ xfp, float2* __restrict__ yf_t, int S) {
  __shared__ float2 wsc[4096];
  __shared__ float2 xsh[256];
  const int k = blockIdx.x & 63;
  const int bq = blockIdx.x >> 6;
  const int tid = threadIdx.x;
#pragma unroll
  for (int j = 0; j < 4; ++j) {
    const int idx = tid + 256 * j;
    float4 vr = ((const float4*)(wrt + (size_t)k * 4096))[idx];
    float4 vi = ((const float4*)(wit + (size_t)k * 4096))[idx];
    wsc[4 * idx + 0] = make_float2(vr.x, vi.x);
    wsc[4 * idx + 1] = make_float2(vr.y, vi.y);
    wsc[4 * idx + 2] = make_float2(vr.z, vi.z);
    wsc[4 * idx + 3] = make_float2(vr.w, vi.w);
  }
  {
    const int R = bq * 256 + tid;        // global row = b*64 + i
    const int rowblk = R >> 5;
    const int rl = R & 31;
    float2 acc = make_float2(0.f, 0.f);
    for (int s = 0; s < S; ++s) {
      const size_t b0 = (((size_t)s * 64 + rowblk) * 2) * 2048;  // plane stride 64*32
      acc.x += xfp[b0 + (size_t)k * 32 + rl];
      acc.y += xfp[b0 + 2048 + (size_t)k * 32 + rl];
    }
    xsh[tid] = acc;
  }
  __syncthreads();
  const int o = tid & 63;
  const int bl = tid >> 6;
  float accr = 0.f, acci = 0.f;
#pragma unroll 8
  for (int i = 0; i < 64; ++i) {
    const float2 xv = xsh[bl * 64 + i];  // broadcast (bl uniform per wave)
    const float2 w = wsc[i * 64 + o];
    accr = fmaf(xv.x, w.x, accr); accr = fmaf(-xv.y, w.y, accr);
    acci = fmaf(xv.x, w.y, acci); acci = fmaf( xv.y, w.x, acci);
  }
  yf_t[(size_t)k * ROWS + bq * 256 + bl * 64 + o] = make_float2(accr, acci);
}

// ---------------------------------------------------------------------------
// K3: 8-fold ICFT with fftshift pairing (round-6 verbatim):
//   out[row,t] = (-1)^t Re sum_k yf[row,k] e^{+2pi i k t/4096}
// grid = 1024: 512 rowgroups (4 rows) x 2 tl-chunks (256 each).
// ---------------------------------------------------------------------------
__global__ __launch_bounds__(256) void icft_kernel(const float2* __restrict__ yf_t,
                                                   float* __restrict__ out) {
  __shared__ float2 ysh[4][66];
  const int rgrp = blockIdx.x >> 1;
  const int tc = blockIdx.x & 1;
  const int row0 = rgrp * 4;
  const int tid = threadIdx.x;
  {
    const int k = tid >> 2;
    const int r = tid & 3;
    ysh[r][k] = yf_t[(size_t)k * ROWS + row0 + r];
  }
  __syncthreads();
  const int tl = tc * 256 + tid;
  float stepr, stepi;
  sincosf(TWO_PI * (float)tl / (float)NT, &stepi, &stepr);
  float wr = 1.f, wi = 0.f;
  float Gr[8][4] = {{0.f}};
  float Gi[8][4] = {{0.f}};   // [0],[4] unused -> dead after unroll
  for (int m = 0; m < 8; ++m) {
#pragma unroll
    for (int cc = 0; cc < 8; ++cc) {
      const int k = 8 * m + cc;
#pragma unroll
      for (int r = 0; r < 4; ++r) {
        const float2 y = ysh[r][k];   // full-wave broadcast
        Gr[cc][r] = fmaf(y.x, wr, Gr[cc][r]);
        Gr[cc][r] = fmaf(-y.y, wi, Gr[cc][r]);
        if (cc != 0 && cc != 4) {
          Gi[cc][r] = fmaf(y.x, wi, Gi[cc][r]);
          Gi[cc][r] = fmaf(y.y, wr, Gi[cc][r]);
        }
      }
      rotm(wr, wi, stepr, stepi);
    }
  }
  const float KK = 0.7071067811865476f;
  const float sgn = (tl & 1) ? -1.f : 1.f;
#pragma unroll
  for (int r = 0; r < 4; ++r) {
    const float Ae = (Gr[0][r] + Gr[2][r]) + (Gr[4][r] + Gr[6][r]);
    const float Ao = (Gr[1][r] + Gr[3][r]) + (Gr[5][r] + Gr[7][r]);
    const float A2 = (Gr[0][r] - Gr[2][r]) + (Gr[4][r] - Gr[6][r]);
    const float B2 = (Gi[1][r] - Gi[3][r]) + (Gi[5][r] - Gi[7][r]);
    const float P  = Gr[0][r] - Gr[4][r];
    const float Qr = (Gr[1][r] - Gr[3][r]) - (Gr[5][r] - Gr[7][r]);
    const float R  = Gi[6][r] - Gi[2][r];
    const float Qi = (Gi[5][r] - Gi[1][r]) + (Gi[7][r] - Gi[3][r]);
    const float U = P + R, V = P - R;
    const float W1 = KK * (Qr + Qi), W2 = KK * (Qr - Qi);
    float* op = out + (size_t)(row0 + r) * NT + tl;
    op[0]    = sgn * (Ae + Ao);
    op[512]  = sgn * (U + W1);
    op[1024] = sgn * (A2 - B2);
    op[1536] = sgn * (V - W2);
    op[2048] = sgn * (Ae - Ao);
    op[2560] = sgn * (U - W1);
    op[3072] = sgn * (A2 + B2);
    op[3584] = sgn * (V + W2);
  }
}

extern "C" void kernel_launch(void* const* d_in, const int* in_sizes, int n_in,
                              void* d_out, int out_size, void* d_ws, size_t ws_size,
                              hipStream_t stream) {
  const float* x      = (const float*)d_in[0];
  const float* w_real = (const float*)d_in[1];
  const float* w_imag = (const float*)d_in[2];
  float* out = (float*)d_out;

  const size_t MB = (size_t)ROWS * MODES * sizeof(float2);  // 1 MiB units
  int S = 16;
  while (S > 4 && (size_t)(S + 5) * MB > ws_size) S >>= 1;

  char* wsp = (char*)d_ws;
  float*  xfp  = (float*)wsp;                         // S MB: [ts][rowblk][pl][k][rl]
  float2* yf_t = (float2*)(wsp + (size_t)S * MB);     // 2 MB: [k][row]
  float*  wrt  = (float*)(wsp + (size_t)(S + 2) * MB);
  float*  wit  = (float*)(wsp + (size_t)(S + 3) * MB);
  unsigned short* Bg = (unsigned short*)(wsp + (size_t)(S + 4) * MB);  // 1 MB

  bgen_kernel<<<256, 256, 0, stream>>>(Bg);
  cft_mfma_kernel<<<64 * S + 128, 256, 0, stream>>>(x, Bg, xfp, w_real, w_imag,
                                                    wrt, wit, S);
  mix_kernel<<<512, 256, 0, stream>>>(wrt, wit, xfp, yf_t, S);
  icft_kernel<<<1024, 256, 0, stream>>>(yf_t, out);
}

// Round 13
// 42.746 us; speedup vs baseline: 1.2384x; 1.0761x over previous
//
#include <hip/hip_runtime.h>
#include <math.h>

#define NT 4096
#define MODES 64
#define ROWS 2048       // B*Ci == B*Co
#define TWO_PI 6.283185307179586f

typedef __attribute__((ext_vector_type(8))) short bf16x8;   // 8 bf16 (4 VGPRs)
typedef __attribute__((ext_vector_type(4))) float f32x4;    // MFMA acc

static __device__ __forceinline__ unsigned short bf16rn(float x) {
  unsigned u = __float_as_uint(x);
  u += 0x7FFFu + ((u >> 16) & 1u);   // round-to-nearest-even
  return (unsigned short)(u >> 16);
}

// ---------------------------------------------------------------------------
// K0: generate both basis tables (one dispatch, 512 blocks).
//  blocks 0..255:  Bg[n][t] (bf16): n<64 cos(2pi n t/4096)/4096, n>=64 -sin/4096
//  blocks 256..511: Cg[t][k2] (bf16): k2<64 cos(2pi k2 t/4096)*(-1)^t,
//                   k2>=64 -sin(2pi (k2-64) t/4096)*(-1)^t   (ICFT basis)
// ---------------------------------------------------------------------------
__global__ __launch_bounds__(256) void bgen_kernel(unsigned short* __restrict__ Bg,
                                                   unsigned short* __restrict__ Cg) {
  const int bx = (int)blockIdx.x;
  if (bx < 256) {
    const int e0 = (bx * 256 + (int)threadIdx.x) * 8;
    const int n = e0 >> 12;
    const int t0 = e0 & 4095;
    const int k = (n < 64) ? n : (n - 64);
    bf16x8 pack;
#pragma unroll
    for (int j = 0; j < 8; ++j) {
      const int ph = (k * (t0 + j)) & (NT - 1);
      float s, c;
      sincosf(TWO_PI * (float)ph / (float)NT, &s, &c);
      const float v = ((n < 64) ? c : -s) * (1.0f / (float)NT);
      pack[j] = (short)bf16rn(v);
    }
    *(bf16x8*)(Bg + e0) = pack;
  } else {
    const int e0 = ((bx - 256) * 256 + (int)threadIdx.x) * 8;
    const int t = e0 >> 7;
    const int k2b = e0 & 127;
    const float sgn = (t & 1) ? -1.f : 1.f;
    bf16x8 pack;
#pragma unroll
    for (int j = 0; j < 8; ++j) {
      const int k2 = k2b + j;
      const int k = (k2 < 64) ? k2 : (k2 - 64);
      const int ph = (k * t) & (NT - 1);
      float s, c;
      sincosf(TWO_PI * (float)ph / (float)NT, &s, &c);
      const float v = ((k2 < 64) ? c : -s) * sgn;
      pack[j] = (short)bf16rn(v);
    }
    *(bf16x8*)(Cg + e0) = pack;
  }
}

// ---------------------------------------------------------------------------
// K1: MFMA CFT partials + fused w-transpose (round-12 verbatim, passing).
// ---------------------------------------------------------------------------
__global__ __launch_bounds__(256) void cft_mfma_kernel(
    const float* __restrict__ x, const unsigned short* __restrict__ Bg,
    float* __restrict__ xfp,
    const float* __restrict__ w_real, const float* __restrict__ w_imag,
    float* __restrict__ wrt, float* __restrict__ wit, int S) {
  __shared__ __align__(16) char smem[24576];
  const int tid = threadIdx.x;
  const int nCft = 64 * S;

  if ((int)blockIdx.x >= nCft) {
    float (*tile)[65] = (float (*)[65])smem;
    const int bx = (int)blockIdx.x - nCft;
    const int sel = bx >> 6;
    const int io0 = (bx & 63) * 64;
    const float* __restrict__ src = sel ? w_imag : w_real;
    float* __restrict__ dst = sel ? wit : wrt;
#pragma unroll
    for (int j = 0; j < 4; ++j) {
      const int idx = tid + j * 256;
      const int r = idx >> 4;
      const int kq = idx & 15;
      float4 v = ((const float4*)src)[(size_t)(io0 + r) * 16 + kq];
      tile[r][4 * kq + 0] = v.x; tile[r][4 * kq + 1] = v.y;
      tile[r][4 * kq + 2] = v.z; tile[r][4 * kq + 3] = v.w;
    }
    __syncthreads();
#pragma unroll
    for (int j = 0; j < 16; ++j) {
      const int idx = tid + j * 256;
      const int k = idx >> 6;
      const int r = idx & 63;
      dst[(size_t)k * 4096 + io0 + r] = tile[r][k];
    }
    return;
  }

  unsigned short* Ah = (unsigned short*)smem;
  unsigned short* Al = (unsigned short*)(smem + 4096);
  unsigned short* Bs = (unsigned short*)(smem + 8192);

  const int rowblk = (int)blockIdx.x / S;
  const int ts = (int)blockIdx.x % S;
  const int row0 = rowblk * 32;
  const int t0 = ts * (NT / S);
  const int subs = (NT / S) / 64;

  const int lane = tid & 63;
  const int w = tid >> 6;

  f32x4 acc[2][2];
#pragma unroll
  for (int mt = 0; mt < 2; ++mt)
#pragma unroll
    for (int nt = 0; nt < 2; ++nt) acc[mt][nt] = (f32x4){0.f, 0.f, 0.f, 0.f};

  const int aru = tid & 7;
  const int arow = tid >> 3;

  for (int sub = 0; sub < subs; ++sub) {
    const int tb = t0 + sub * 64;
    __syncthreads();
    {
      const float* xp = x + (size_t)(row0 + arow) * NT + tb + aru * 8;
      const float4 v0 = *(const float4*)xp;
      const float4 v1 = *(const float4*)(xp + 4);
      float xv[8] = {v0.x, v0.y, v0.z, v0.w, v1.x, v1.y, v1.z, v1.w};
      bf16x8 ph, pl;
#pragma unroll
      for (int j = 0; j < 8; ++j) {
        const unsigned short h = bf16rn(xv[j]);
        ph[j] = (short)h;
        const float hf = __uint_as_float((unsigned)h << 16);
        pl[j] = (short)bf16rn(xv[j] - hf);
      }
      const int col = (aru ^ (arow & 7)) * 8;
      *(bf16x8*)(Ah + arow * 64 + col) = ph;
      *(bf16x8*)(Al + arow * 64 + col) = pl;
    }
#pragma unroll
    for (int it = 0; it < 4; ++it) {
      const int idx = tid + it * 256;
      const int ku = idx & 7;
      const int n = idx >> 3;
      const bf16x8 v = *(const bf16x8*)(Bg + (size_t)n * NT + tb + ku * 8);
      const int col = (ku ^ (n & 7)) * 8;
      *(bf16x8*)(Bs + n * 64 + col) = v;
    }
    __syncthreads();
    const int kg = lane >> 4;
#pragma unroll
    for (int ks = 0; ks < 2; ++ks) {
      bf16x8 bf[2];
#pragma unroll
      for (int nt = 0; nt < 2; ++nt) {
        const int n = w * 32 + nt * 16 + (lane & 15);
        const int col = ((ks * 4 + kg) ^ (n & 7)) * 8;
        bf[nt] = *(const bf16x8*)(Bs + n * 64 + col);
      }
#pragma unroll
      for (int mt = 0; mt < 2; ++mt) {
        const int row = mt * 16 + (lane & 15);
        const int col = ((ks * 4 + kg) ^ (row & 7)) * 8;
        const bf16x8 ah = *(const bf16x8*)(Ah + row * 64 + col);
        const bf16x8 al = *(const bf16x8*)(Al + row * 64 + col);
#pragma unroll
        for (int nt = 0; nt < 2; ++nt) {
          acc[mt][nt] = __builtin_amdgcn_mfma_f32_16x16x32_bf16(ah, bf[nt], acc[mt][nt], 0, 0, 0);
          acc[mt][nt] = __builtin_amdgcn_mfma_f32_16x16x32_bf16(al, bf[nt], acc[mt][nt], 0, 0, 0);
        }
      }
    }
  }
  const int nb = w * 32 + (lane & 15);
#pragma unroll
  for (int nt = 0; nt < 2; ++nt) {
    const int n = nb + nt * 16;
    const int plane = n >> 6;
    const int kk = n & 63;
#pragma unroll
    for (int mt = 0; mt < 2; ++mt) {
      const int rl = mt * 16 + (lane >> 4) * 4;
      float4 st = {acc[mt][nt][0], acc[mt][nt][1], acc[mt][nt][2], acc[mt][nt][3]};
      ((float4*)xfp)[((((size_t)ts * 64 + rowblk) * 2 + plane) * 64 + kk) * 8 + (rl >> 2)] = st;
    }
  }
}

// ---------------------------------------------------------------------------
// K2: sum partials + spectral mix (round-12 verbatim, passing).
// ---------------------------------------------------------------------------
__global__ __launch_bounds__(256) void mix_kernel(
    const float* __restrict__ wrt, const float* __restrict__ wit,
    const float* __restrict__ xfp, float2* __restrict__ yf_t, int S) {
  __shared__ float2 wsc[4096];
  __shared__ float2 xsh[256];
  const int k = blockIdx.x & 63;
  const int bq = blockIdx.x >> 6;
  const int tid = threadIdx.x;
#pragma unroll
  for (int j = 0; j < 4; ++j) {
    const int idx = tid + 256 * j;
    float4 vr = ((const float4*)(wrt + (size_t)k * 4096))[idx];
    float4 vi = ((const float4*)(wit + (size_t)k * 4096))[idx];
    wsc[4 * idx + 0] = make_float2(vr.x, vi.x);
    wsc[4 * idx + 1] = make_float2(vr.y, vi.y);
    wsc[4 * idx + 2] = make_float2(vr.z, vi.z);
    wsc[4 * idx + 3] = make_float2(vr.w, vi.w);
  }
  {
    const int R = bq * 256 + tid;
    const int rowblk = R >> 5;
    const int rl = R & 31;
    float2 acc = make_float2(0.f, 0.f);
    for (int s = 0; s < S; ++s) {
      const size_t b0 = (((size_t)s * 64 + rowblk) * 2) * 2048;
      acc.x += xfp[b0 + (size_t)k * 32 + rl];
      acc.y += xfp[b0 + 2048 + (size_t)k * 32 + rl];
    }
    xsh[tid] = acc;
  }
  __syncthreads();
  const int o = tid & 63;
  const int bl = tid >> 6;
  float accr = 0.f, acci = 0.f;
#pragma unroll 8
  for (int i = 0; i < 64; ++i) {
    const float2 xv = xsh[bl * 64 + i];
    const float2 w = wsc[i * 64 + o];
    accr = fmaf(xv.x, w.x, accr); accr = fmaf(-xv.y, w.y, accr);
    acci = fmaf(xv.x, w.y, acci); acci = fmaf( xv.y, w.x, acci);
  }
  yf_t[(size_t)k * ROWS + bq * 256 + bl * 64 + o] = make_float2(accr, acci);
}

// ---------------------------------------------------------------------------
// K3: MFMA ICFT. Out[2048,4096] = Y2[2048,128] x C[128,4096], C from Cg
// (fftshift sign folded in). Single bf16 (128-term sum of ~1e-5 terms ->
// error ~3e-7, no hi/lo split needed).
// Block: 32 rows x 256 t, 4 waves. Y2 staged once (swizzled bf16 LDS, then
// A-frags in registers); C staged per 64-t sub (16 KB); wave w owns t-tile w.
// grid = 1024: 64 rowgroups x 16 t-groups.
// ---------------------------------------------------------------------------
__global__ __launch_bounds__(256) void icft_mfma_kernel(
    const float2* __restrict__ yf_t, const unsigned short* __restrict__ Cg,
    float* __restrict__ out) {
  __shared__ __align__(16) char smem[24576];
  unsigned short* Ay = (unsigned short*)smem;          // [32 rows][128 k2], 8 KB
  unsigned short* Cs = (unsigned short*)(smem + 8192); // [64 t][128 k2], 16 KB
  const int tid = threadIdx.x;
  const int rgrp = (int)blockIdx.x >> 4;
  const int tgrp = (int)blockIdx.x & 15;
  const int row0 = rgrp * 32;
  const int tb0 = tgrp * 256;
  const int lane = tid & 63;
  const int w = tid >> 6;

  // ---- Y stage: yf_t[k][row0..row0+32) -> Ay[row][k2] bf16, unit-swizzled ----
#pragma unroll
  for (int it = 0; it < 8; ++it) {
    const int idx = tid + it * 256;
    const int k = idx >> 5;          // 0..63
    const int rl = idx & 31;
    const float2 y = yf_t[(size_t)k * ROWS + row0 + rl];
    const int ur = (k >> 3) ^ (rl & 7);          // re unit 0..7
    Ay[rl * 128 + ur * 8 + (k & 7)] = bf16rn(y.x);
    Ay[rl * 128 + (8 | ur) * 8 + (k & 7)] = bf16rn(y.y);  // im unit 8..15
  }
  __syncthreads();

  // ---- A-fragments to registers: frag[mt][ks], row = mt*16+(lane&15) ----
  bf16x8 afr[2][4];
#pragma unroll
  for (int mt = 0; mt < 2; ++mt) {
    const int row = mt * 16 + (lane & 15);
#pragma unroll
    for (int ks = 0; ks < 4; ++ks) {
      const int unit = ks * 4 + (lane >> 4);
      const int cu = unit ^ (row & 7);           // XOR low 3 bits, half-preserving
      afr[mt][ks] = *(const bf16x8*)(Ay + row * 128 + cu * 8);
    }
  }

  for (int sub = 0; sub < 4; ++sub) {
    const int tb = tb0 + sub * 64;
    __syncthreads();
    // C stage: Cg[t][k2] rows tb..tb+64 -> Cs[tl][128], unit-swizzled
#pragma unroll
    for (int it = 0; it < 4; ++it) {
      const int idx = tid + it * 256;   // 0..1023
      const int ku = idx & 15;
      const int tl = idx >> 4;          // 0..63
      const bf16x8 v = *(const bf16x8*)(Cg + (size_t)(tb + tl) * 128 + ku * 8);
      Cs[tl * 128 + (ku ^ (tl & 7)) * 8] = 0;  // placeholder overwritten below
      *(bf16x8*)(Cs + tl * 128 + (ku ^ (tl & 7)) * 8) = v;
    }
    __syncthreads();
    // wave w owns t-tile [tb + w*16, +16)
    const int tl = w * 16 + (lane & 15);
    f32x4 acc[2];
    acc[0] = (f32x4){0.f, 0.f, 0.f, 0.f};
    acc[1] = (f32x4){0.f, 0.f, 0.f, 0.f};
#pragma unroll
    for (int ks = 0; ks < 4; ++ks) {
      const int unit = ks * 4 + (lane >> 4);
      const int cu = unit ^ (tl & 7);
      const bf16x8 bf = *(const bf16x8*)(Cs + tl * 128 + cu * 8);
      acc[0] = __builtin_amdgcn_mfma_f32_16x16x32_bf16(afr[0][ks], bf, acc[0], 0, 0, 0);
      acc[1] = __builtin_amdgcn_mfma_f32_16x16x32_bf16(afr[1][ks], bf, acc[1], 0, 0, 0);
    }
    const int t = tb + tl;
#pragma unroll
    for (int mt = 0; mt < 2; ++mt) {
      const int rbase = row0 + mt * 16 + (lane >> 4) * 4;
#pragma unroll
      for (int reg = 0; reg < 4; ++reg) {
        out[(size_t)(rbase + reg) * NT + t] = acc[mt][reg];
      }
    }
  }
}

extern "C" void kernel_launch(void* const* d_in, const int* in_sizes, int n_in,
                              void* d_out, int out_size, void* d_ws, size_t ws_size,
                              hipStream_t stream) {
  const float* x      = (const float*)d_in[0];
  const float* w_real = (const float*)d_in[1];
  const float* w_imag = (const float*)d_in[2];
  float* out = (float*)d_out;

  const size_t MB = (size_t)ROWS * MODES * sizeof(float2);  // 1 MiB units
  int S = 16;
  while (S > 4 && (size_t)(S + 6) * MB > ws_size) S >>= 1;

  char* wsp = (char*)d_ws;
  float*  xfp  = (float*)wsp;                         // S MB
  float2* yf_t = (float2*)(wsp + (size_t)S * MB);     // 2 MB: [k][row]
  float*  wrt  = (float*)(wsp + (size_t)(S + 2) * MB);
  float*  wit  = (float*)(wsp + (size_t)(S + 3) * MB);
  unsigned short* Bg = (unsigned short*)(wsp + (size_t)(S + 4) * MB);  // 1 MB
  unsigned short* Cg = (unsigned short*)(wsp + (size_t)(S + 5) * MB);  // 1 MB

  bgen_kernel<<<512, 256, 0, stream>>>(Bg, Cg);
  cft_mfma_kernel<<<64 * S + 128, 256, 0, stream>>>(x, Bg, xfp, w_real, w_imag,
                                                    wrt, wit, S);
  mix_kernel<<<512, 256, 0, stream>>>(wrt, wit, xfp, yf_t, S);
  icft_mfma_kernel<<<1024, 256, 0, stream>>>(yf_t, Cg, out);
}